// Round 3
// baseline (1728.195 us; speedup 1.0000x reference)
//
#include <hip/hip_runtime.h>
#include <math.h>

#define BSZ 2
#define CHN 64
#define NPT 400
#define LW  12
#define DM  128
#define NH  8
#define HDM 16
#define FFD 1024
#define NTOK (BSZ*LW*NPT)   // 9600
// token' ordering everywhere: token = b*4800 + n*12 + l  (l innermost)

// ------------------------------------------------------------------
// Stage A: QKV projections + per-head l2norm.
// q/k/v layout: [b][l][h][n][d]  (contiguous 400x16 slice per (b,l,h))
// ------------------------------------------------------------------
#define TA 16
__global__ __launch_bounds__(128) void stage_a(
    const float* __restrict__ x, const float* __restrict__ xa1, const float* __restrict__ xa2,
    const float* __restrict__ WQ1, const float* __restrict__ bQ1,
    const float* __restrict__ WQ2, const float* __restrict__ bQ2,
    const float* __restrict__ WK1, const float* __restrict__ bK1,
    const float* __restrict__ WK2, const float* __restrict__ bK2,
    const float* __restrict__ WV,  const float* __restrict__ bV,
    float* __restrict__ q1n, float* __restrict__ q2n,
    float* __restrict__ k1n, float* __restrict__ k2n, float* __restrict__ vv)
{
  __shared__ float xv[TA][65], a1v[TA][65], a2v[TA][65];
  const int tid = threadIdx.x;
  const int t0 = blockIdx.x * TA;
  const int b  = t0 / 4800;
  const int nl0 = t0 % 4800;          // 16-aligned, block stays within one b
  {
    const float4* xg  = (const float4*)x;
    const float4* a1g = (const float4*)xa1;
    const float4* a2g = (const float4*)xa2;
    for (int i = tid; i < 256; i += 128) {
      int c = i >> 2, q = i & 3;
      int src = ((b*64 + c)*4800 + nl0)/4 + q;   // float4-aligned
      float4 xq = xg[src], a1q = a1g[src], a2q = a2g[src];
      int tt = q*4;
      xv[tt+0][c]=xq.x;  xv[tt+1][c]=xq.y;  xv[tt+2][c]=xq.z;  xv[tt+3][c]=xq.w;
      a1v[tt+0][c]=a1q.x; a1v[tt+1][c]=a1q.y; a1v[tt+2][c]=a1q.z; a1v[tt+3][c]=a1q.w;
      a2v[tt+0][c]=a2q.x; a2v[tt+1][c]=a2q.y; a2v[tt+2][c]=a2q.z; a2v[tt+3][c]=a2q.w;
    }
  }
  __syncthreads();
  const int d = tid;  // 0..127
  float aq1[TA], aq2[TA], ak1[TA], ak2[TA], av[TA];
  float b1 = bQ1[d], b2 = bQ2[d], b3 = bK1[d], b4 = bK2[d], b5 = bV[d];
  #pragma unroll
  for (int t = 0; t < TA; ++t) { aq1[t]=b1; aq2[t]=b2; ak1[t]=b3; ak2[t]=b4; av[t]=b5; }
  for (int c = 0; c < CHN; ++c) {
    float w1 = WQ1[c*DM + d], w2 = WQ2[c*DM + d], w3 = WK1[c*DM + d],
          w4 = WK2[c*DM + d], w5 = WV[c*DM + d];
    #pragma unroll
    for (int t = 0; t < TA; ++t) {
      float xc = xv[t][c], x1 = a1v[t][c], x2 = a2v[t][c];
      aq1[t] += x1*w1; aq2[t] += x2*w2; ak1[t] += xc*w3; ak2[t] += xc*w4; av[t] += xc*w5;
    }
  }
  const int h = d >> 4, dd = d & 15;
  #pragma unroll
  for (int t = 0; t < TA; ++t) {
    float s1 = aq1[t]*aq1[t], s2 = aq2[t]*aq2[t], s3 = ak1[t]*ak1[t], s4 = ak2[t]*ak2[t];
    #pragma unroll
    for (int m = 1; m < 16; m <<= 1) {
      s1 += __shfl_xor(s1, m); s2 += __shfl_xor(s2, m);
      s3 += __shfl_xor(s3, m); s4 += __shfl_xor(s4, m);
    }
    float i1 = 1.f/fmaxf(sqrtf(s1),1e-12f), i2 = 1.f/fmaxf(sqrtf(s2),1e-12f),
          i3 = 1.f/fmaxf(sqrtf(s3),1e-12f), i4 = 1.f/fmaxf(sqrtf(s4),1e-12f);
    int nl = nl0 + t;
    int n = nl / 12, l = nl % 12;
    int base = (((b*LW + l)*NH + h)*NPT + n)*HDM + dd;
    q1n[base] = aq1[t]*i1; q2n[base] = aq2[t]*i2;
    k1n[base] = ak1[t]*i3; k2n[base] = ak2[t]*i4; vv[base] = av[t];
  }
}

// ------------------------------------------------------------------
// Stage B: fused dual-cosine attention + exact top-k dual softmax + PV
// Grid: (b,h,l, split s of 100 rows) = 768 WGs x 256 threads
// LDS: k1/k2 only (51.3 KB) -> 3 WGs/CU; v read from global (L1/L2)
// ------------------------------------------------------------------
__device__ __forceinline__ unsigned okey(float xf) {
  unsigned u = __float_as_uint(xf);
  return (u & 0x80000000u) ? ~u : (u | 0x80000000u);
}
__device__ __forceinline__ float dekey(unsigned k) {
  unsigned u = (k & 0x80000000u) ? (k & 0x7FFFFFFFu) : ~k;
  return __uint_as_float(u);
}

__global__ __launch_bounds__(256, 3) void stage_b(
    const float* __restrict__ q1n, const float* __restrict__ q2n,
    const float* __restrict__ k1n, const float* __restrict__ k2n,
    const float* __restrict__ vv,
    const float* __restrict__ temperature, const float* __restrict__ alphas,
    float* __restrict__ attn_o, float* __restrict__ p2_o, float* __restrict__ oa)
{
  // d-chunk planes, stride 401 float4 per plane: stride-1 b128 reads, conflict-free
  __shared__ float4 k1s[4*401], k2s[4*401];
  int wg = blockIdx.x;
  const int s = wg & 3; wg >>= 2;
  const int l = wg % LW; wg /= LW;
  const int h = wg & 7; const int b = wg >> 3;
  const int tid = threadIdx.x, lane = tid & 63, wave = tid >> 6;

  const int slice = (b*LW + l)*NH + h;          // internal q/k/v layout [b][l][h]
  const int oslice = (b*NH + h)*LW + l;         // OUTPUT layout [b][h][l]
  const float4* k1g = (const float4*)(k1n + slice*NPT*HDM);
  const float4* k2g = (const float4*)(k2n + slice*NPT*HDM);
  const float4* vg  = (const float4*)(vv  + slice*NPT*HDM);
  for (int i = tid; i < NPT*4; i += 256) {
    int m = i >> 2, w4 = i & 3;
    k1s[w4*401 + m] = k1g[i];
    k2s[w4*401 + m] = k2g[i];
  }
  __syncthreads();

  const float temp = temperature[h];
  float a0 = alphas[0], a1 = alphas[1];
  float amx = fmaxf(a0, a1);
  float e0 = __expf(a0 - amx), e1 = __expf(a1 - amx);
  float al0 = e0/(e0+e1), al1 = e1/(e0+e1);

  const float* q1base = q1n + slice*NPT*HDM;
  const float* q2base = q2n + slice*NPT*HDM;
  float* attn_base = attn_o + (size_t)oslice*NPT*NPT;
  float* p2_base   = p2_o   + (size_t)oslice*NPT*NPT;

  for (int bi = wave; bi < 25; bi += 4) {
    const int nb = s*100 + bi*4;    // rows nb..nb+3
    float sc[4][7];
    #pragma unroll
    for (int r = 0; r < 4; ++r)
      #pragma unroll
      for (int j = 0; j < 7; ++j) sc[r][j] = 0.f;

    // ---- scores: Q1.K1 + Q2.K2 over d (16+16), 4 rows x 7 m's/lane ----
    #pragma unroll
    for (int ch = 0; ch < 4; ++ch) {
      float4 q1c[4], q2c[4];
      #pragma unroll
      for (int r = 0; r < 4; ++r) {
        q1c[r] = *(const float4*)(q1base + (nb+r)*HDM + ch*4);
        q2c[r] = *(const float4*)(q2base + (nb+r)*HDM + ch*4);
      }
      #pragma unroll
      for (int j = 0; j < 7; ++j) {
        int m = lane + 64*j;
        if (j < 6 || lane < 16) {
          float4 kc1 = k1s[ch*401 + m];
          float4 kc2 = k2s[ch*401 + m];
          #pragma unroll
          for (int r = 0; r < 4; ++r) {
            sc[r][j] += q1c[r].x*kc1.x + q1c[r].y*kc1.y + q1c[r].z*kc1.z + q1c[r].w*kc1.w
                      + q2c[r].x*kc2.x + q2c[r].y*kc2.y + q2c[r].z*kc2.z + q2c[r].w*kc2.w;
          }
        }
      }
    }
    // ---- temperature + attn output ----
    #pragma unroll
    for (int r = 0; r < 4; ++r) {
      #pragma unroll
      for (int j = 0; j < 7; ++j) {
        sc[r][j] *= temp;
        int m = lane + 64*j;
        if (j < 6 || lane < 16) attn_base[(nb + r)*NPT + m] = sc[r][j];
      }
    }
    // ---- per-row: exact top-k select (interleaved dual search) + softmax ----
    #pragma unroll
    for (int r = 0; r < 4; ++r) {
      unsigned key[7];
      unsigned kmx = 0u, kmn = 0xFFFFFFFFu;
      #pragma unroll
      for (int j = 0; j < 7; ++j) {
        bool valid = (j < 6) || (lane < 16);
        unsigned kk = valid ? okey(sc[r][j]) : 0u;
        key[j] = kk;
        kmx = kk > kmx ? kk : kmx;
        unsigned kn = valid ? kk : 0xFFFFFFFFu;
        kmn = kn < kmn ? kn : kmn;
      }
      #pragma unroll
      for (int m2 = 1; m2 < 64; m2 <<= 1) {
        unsigned ox = __shfl_xor(kmx, m2); kmx = ox > kmx ? ox : kmx;
        unsigned on = __shfl_xor(kmn, m2); kmn = on < kmn ? on : kmn;
      }
      float am = dekey(kmx);              // exact row max (for softmax)
      unsigned diff = kmx ^ kmn;
      unsigned p1, p2u;
      if (diff == 0u) {
        p1 = kmx; p2u = kmx;
      } else {
        int fd = 31 - __clz(diff);
        unsigned hi = (fd >= 31) ? 0u : (~0u << (fd+1));
        p1 = kmx & hi; p2u = p1;          // common prefix of all keys
        bool d1 = false, d2 = false;
        #pragma clang loop unroll(disable)
        for (int bit = fd; bit >= 0; --bit) {
          unsigned msk = 1u << bit;
          if (!d1) {
            unsigned T1 = p1 | msk;
            int c1 = 0;
            #pragma unroll
            for (int j = 0; j < 7; ++j) c1 += __popcll(__ballot(key[j] >= T1));
            if (c1 >= 200) { p1 = T1; d1 = (c1 == 200); }
          }
          if (!d2) {
            unsigned T2 = p2u | msk;
            int c2 = 0;
            #pragma unroll
            for (int j = 0; j < 7; ++j) c2 += __popcll(__ballot(key[j] >= T2));
            if (c2 >= 100) { p2u = T2; d2 = (c2 == 100); }
          }
          if (d1 & d2) break;
        }
      }
      float e[7]; float s1 = 0.f, s2 = 0.f;
      #pragma unroll
      for (int j = 0; j < 7; ++j) {
        e[j] = ((j < 6) || (lane < 16)) ? __expf(sc[r][j] - am) : 0.f;
        s1 += (key[j] >= p1)  ? e[j] : 0.f;
        s2 += (key[j] >= p2u) ? e[j] : 0.f;
      }
      #pragma unroll
      for (int m2 = 1; m2 < 64; m2 <<= 1) { s1 += __shfl_xor(s1, m2); s2 += __shfl_xor(s2, m2); }
      float rz1 = 1.f / s1, rz2 = 1.f / s2;
      float c1f = al0 * rz1, c2f = al1 * rz2;
      #pragma unroll
      for (int j = 0; j < 7; ++j) {
        int m = lane + 64*j;
        float p2v = (key[j] >= p2u) ? e[j]*rz2 : 0.f;
        if ((j < 6) || (lane < 16)) p2_base[(nb + r)*NPT + m] = p2v;
        sc[r][j] = e[j] * (((key[j] >= p1) ? c1f : 0.f) + ((key[j] >= p2u) ? c2f : 0.f));
      }
    }
    // ---- PV: out[r][d] = sum_m w[r][m] * v[m][d]; v from global (L1/L2) ----
    float buf[64];
    #pragma unroll
    for (int i = 0; i < 64; ++i) buf[i] = 0.f;
    #pragma unroll
    for (int j = 0; j < 7; ++j) {
      int m = lane + 64*j;
      if (j < 6 || lane < 16) {
        const float4* vp = vg + m*4;
        float4 w0 = vp[0], w1 = vp[1], w2 = vp[2], w3 = vp[3];
        #pragma unroll
        for (int r = 0; r < 4; ++r) {
          float wr = sc[r][j];
          buf[r*16+ 0] += wr*w0.x; buf[r*16+ 1] += wr*w0.y; buf[r*16+ 2] += wr*w0.z; buf[r*16+ 3] += wr*w0.w;
          buf[r*16+ 4] += wr*w1.x; buf[r*16+ 5] += wr*w1.y; buf[r*16+ 6] += wr*w1.z; buf[r*16+ 7] += wr*w1.w;
          buf[r*16+ 8] += wr*w2.x; buf[r*16+ 9] += wr*w2.y; buf[r*16+10] += wr*w2.z; buf[r*16+11] += wr*w2.w;
          buf[r*16+12] += wr*w3.x; buf[r*16+13] += wr*w3.y; buf[r*16+14] += wr*w3.z; buf[r*16+15] += wr*w3.w;
        }
      }
    }
    // ---- 64-element reduce-scatter across lanes (lane ends owning idx=lane) ----
    #pragma unroll
    for (int st = 0; st < 6; ++st) {
      int bsel = (lane >> st) & 1;
      #pragma unroll
      for (int u = 0; u < (64 >> (st+1)); ++u) {
        float lo = buf[2*u], hi = buf[2*u+1];
        float keep = bsel ? hi : lo;
        float send = bsel ? lo : hi;
        float recv = __shfl_xor(send, 1 << st);
        buf[u] = keep + recv;
      }
    }
    int rr = lane >> 4, ddd = lane & 15;
    oa[((size_t)b*4800 + (size_t)(nb + rr)*12 + l)*DM + h*HDM + ddd] = buf[0];
  }
}

// ------------------------------------------------------------------
// Stage C: Wo + residual + LN1 + FF + LN2 + coalesced transpose-out
// Grid: 300 WGs x 256 threads, 32 tokens/WG (token' = b*4800+n*12+l)
// ------------------------------------------------------------------
#define TC 32
__global__ __launch_bounds__(256, 2) void stage_c(
    const float* __restrict__ oa, const float* __restrict__ x,
    const float* __restrict__ Wo, const float* __restrict__ bo,
    const float* __restrict__ Wf1, const float* __restrict__ bf1,
    const float* __restrict__ Wf2, const float* __restrict__ bf2,
    const float* __restrict__ g1, const float* __restrict__ be1,
    const float* __restrict__ g2, const float* __restrict__ be2,
    float* __restrict__ outp)
{
  __shared__ float4 oa_lds[TC*32];   // 16 KB
  __shared__ float  xs[TC][65];      // 8.3 KB (x in, y out)
  __shared__ float4 y1_lds[TC*16];   // 8 KB
  __shared__ float4 act_lds[TC*64];  // 32 KB
  const int tid = threadIdx.x;
  const int t0 = blockIdx.x * TC;
  const int b = t0 / 4800, nl0 = t0 % 4800;   // 32 | 4800
  const float4* oag = (const float4*)(oa + t0*DM);
  for (int i = tid; i < TC*32; i += 256) oa_lds[i] = oag[i];
  {
    const float4* xg = (const float4*)x;
    for (int i = tid; i < 512; i += 256) {
      int c = i >> 3, q = i & 7;
      float4 xq = xg[((b*64 + c)*4800 + nl0)/4 + q];
      int tt = q*4;
      xs[tt+0][c]=xq.x; xs[tt+1][c]=xq.y; xs[tt+2][c]=xq.z; xs[tt+3][c]=xq.w;
    }
  }
  __syncthreads();

  const int c = tid & 63, g = tid >> 6;   // tokens tt = g + 4k, k=0..7
  float bo_c = bo[c], g1c = g1[c], be1c = be1[c], g2c = g2[c], be2c = be2[c], bf2c = bf2[c];

  // P1: o1 = oa @ Wo + bo
  float o1[8];
  #pragma unroll
  for (int k = 0; k < 8; ++k) o1[k] = bo_c;
  for (int d4 = 0; d4 < 32; ++d4) {
    float w0 = Wo[(4*d4+0)*CHN + c];
    float w1 = Wo[(4*d4+1)*CHN + c];
    float w2 = Wo[(4*d4+2)*CHN + c];
    float w3 = Wo[(4*d4+3)*CHN + c];
    #pragma unroll
    for (int k = 0; k < 8; ++k) {
      float4 u = oa_lds[(g + 4*k)*32 + d4];
      o1[k] += u.x*w0 + u.y*w1 + u.z*w2 + u.w*w3;
    }
  }
  // residual + LN1
  float y1r[8];
  #pragma unroll
  for (int k = 0; k < 8; ++k) {
    float val = o1[k] + xs[g + 4*k][c];
    float sm = val, sq = val*val;
    #pragma unroll
    for (int m2 = 1; m2 < 64; m2 <<= 1) { sm += __shfl_xor(sm, m2); sq += __shfl_xor(sq, m2); }
    float mean = sm * (1.f/64.f);
    float var = sq * (1.f/64.f) - mean*mean;
    float y = (val - mean) * rsqrtf(var + 1e-5f) * g1c + be1c;
    y1r[k] = y;
    ((float*)y1_lds)[(g + 4*k)*CHN + c] = y;
  }
  __syncthreads();

  float o2a[8];
  #pragma unroll
  for (int k = 0; k < 8; ++k) o2a[k] = 0.f;

  for (int fb = 0; fb < 4; ++fb) {
    // 2a: act = relu(y1 @ Wf1 + bf1) for 256 f's
    {
      const int ft = tid & 63, ga = tid >> 6;
      const int f = fb*256 + ft*4;
      float4 facc[8];
      float4 bb = *(const float4*)(bf1 + f);
      #pragma unroll
      for (int k = 0; k < 8; ++k) facc[k] = bb;
      for (int c4 = 0; c4 < 16; ++c4) {
        float4 w0 = *(const float4*)(Wf1 + (4*c4+0)*FFD + f);
        float4 w1 = *(const float4*)(Wf1 + (4*c4+1)*FFD + f);
        float4 w2 = *(const float4*)(Wf1 + (4*c4+2)*FFD + f);
        float4 w3 = *(const float4*)(Wf1 + (4*c4+3)*FFD + f);
        #pragma unroll
        for (int k = 0; k < 8; ++k) {
          float4 y4 = y1_lds[(ga + 4*k)*16 + c4];
          facc[k].x += y4.x*w0.x + y4.y*w1.x + y4.z*w2.x + y4.w*w3.x;
          facc[k].y += y4.x*w0.y + y4.y*w1.y + y4.z*w2.y + y4.w*w3.y;
          facc[k].z += y4.x*w0.z + y4.y*w1.z + y4.z*w2.z + y4.w*w3.z;
          facc[k].w += y4.x*w0.w + y4.y*w1.w + y4.z*w2.w + y4.w*w3.w;
        }
      }
      #pragma unroll
      for (int k = 0; k < 8; ++k) {
        float4 rv;
        rv.x = fmaxf(facc[k].x, 0.f); rv.y = fmaxf(facc[k].y, 0.f);
        rv.z = fmaxf(facc[k].z, 0.f); rv.w = fmaxf(facc[k].w, 0.f);
        act_lds[(ga + 4*k)*64 + ft] = rv;
      }
    }
    __syncthreads();
    // 2b: o2 += act @ Wf2
    for (int f4 = 0; f4 < 64; ++f4) {
      int f = fb*256 + f4*4;
      float w0 = Wf2[(f+0)*CHN + c];
      float w1 = Wf2[(f+1)*CHN + c];
      float w2 = Wf2[(f+2)*CHN + c];
      float w3 = Wf2[(f+3)*CHN + c];
      #pragma unroll
      for (int k = 0; k < 8; ++k) {
        float4 a4 = act_lds[(g + 4*k)*64 + f4];
        o2a[k] += a4.x*w0 + a4.y*w1 + a4.z*w2 + a4.w*w3;
      }
    }
    __syncthreads();
  }
  // P3: + bf2, residual y1, LN2 -> stash y into xs, then coalesced store
  #pragma unroll
  for (int k = 0; k < 8; ++k) {
    float val = y1r[k] + o2a[k] + bf2c;
    float sm = val, sq = val*val;
    #pragma unroll
    for (int m2 = 1; m2 < 64; m2 <<= 1) { sm += __shfl_xor(sm, m2); sq += __shfl_xor(sq, m2); }
    float mean = sm * (1.f/64.f);
    float var = sq * (1.f/64.f) - mean*mean;
    float y = (val - mean) * rsqrtf(var + 1e-5f) * g2c + be2c;
    xs[g + 4*k][c] = y;
  }
  __syncthreads();
  {
    float4* og = (float4*)outp;
    for (int i = tid; i < 512; i += 256) {
      int cc = i >> 3, q = i & 7;
      int tt = q*4;
      float4 yq;
      yq.x = xs[tt+0][cc]; yq.y = xs[tt+1][cc]; yq.z = xs[tt+2][cc]; yq.w = xs[tt+3][cc];
      og[((b*64 + cc)*4800 + nl0)/4 + q] = yq;
    }
  }
}

// ------------------------------------------------------------------
extern "C" void kernel_launch(void* const* d_in, const int* in_sizes, int n_in,
                              void* d_out, int out_size, void* d_ws, size_t ws_size,
                              hipStream_t stream) {
  const float* x    = (const float*)d_in[0];
  const float* xa1  = (const float*)d_in[1];
  const float* xa2  = (const float*)d_in[2];
  const float* WQ1  = (const float*)d_in[3];
  const float* bQ1  = (const float*)d_in[4];
  const float* WQ2  = (const float*)d_in[5];
  const float* bQ2  = (const float*)d_in[6];
  const float* WK1  = (const float*)d_in[7];
  const float* bK1  = (const float*)d_in[8];
  const float* WK2  = (const float*)d_in[9];
  const float* bK2  = (const float*)d_in[10];
  const float* WV   = (const float*)d_in[11];
  const float* bV   = (const float*)d_in[12];
  const float* Wo   = (const float*)d_in[13];
  const float* bo   = (const float*)d_in[14];
  const float* Wf1  = (const float*)d_in[15];
  const float* bf1  = (const float*)d_in[16];
  const float* Wf2  = (const float*)d_in[17];
  const float* bf2  = (const float*)d_in[18];
  const float* g1   = (const float*)d_in[19];
  const float* be1  = (const float*)d_in[20];
  const float* g2   = (const float*)d_in[21];
  const float* be2  = (const float*)d_in[22];
  const float* temp = (const float*)d_in[23];
  const float* alph = (const float*)d_in[24];

  float* outp   = (float*)d_out;
  float* attn_o = outp + (size_t)BSZ*CHN*NPT*LW;          // 614400
  float* p2_o   = attn_o + (size_t)BSZ*NH*LW*NPT*NPT;     // +30720000

  const size_t SLICE = (size_t)BSZ*LW*NH*NPT*HDM;         // 2457600
  float* w   = (float*)d_ws;
  float* q1n = w;             w += SLICE;
  float* q2n = w;             w += SLICE;
  float* k1n = w;             w += SLICE;
  float* k2n = w;             w += SLICE;
  float* vv  = w;             w += SLICE;
  float* oa  = w;             w += (size_t)NTOK*DM;

  stage_a<<<NTOK/TA, 128, 0, stream>>>(x, xa1, xa2, WQ1, bQ1, WQ2, bQ2,
                                       WK1, bK1, WK2, bK2, WV, bV,
                                       q1n, q2n, k1n, k2n, vv);
  stage_b<<<BSZ*NH*LW*4, 256, 0, stream>>>(q1n, q2n, k1n, k2n, vv,
                                           temp, alph, attn_o, p2_o, oa);
  stage_c<<<NTOK/TC, 256, 0, stream>>>(oa, x, Wo, bo, Wf1, bf1, Wf2, bf2,
                                       g1, be1, g2, be2, outp);
}

// Round 4
// 1298.342 us; speedup vs baseline: 1.3311x; 1.3311x over previous
//
#include <hip/hip_runtime.h>
#include <math.h>

#define BSZ 2
#define CHN 64
#define NPT 400
#define LW  12
#define DM  128
#define NH  8
#define HDM 16
#define FFD 1024
#define NTOK (BSZ*LW*NPT)   // 9600
// token' ordering everywhere: token = b*4800 + n*12 + l  (l innermost)

// ------------------------------------------------------------------
// Stage A: QKV projections + per-head l2norm.
// q/k/v layout: [b][l][h][n][d]  (contiguous 400x16 slice per (b,l,h))
// ------------------------------------------------------------------
#define TA 16
__global__ __launch_bounds__(128) void stage_a(
    const float* __restrict__ x, const float* __restrict__ xa1, const float* __restrict__ xa2,
    const float* __restrict__ WQ1, const float* __restrict__ bQ1,
    const float* __restrict__ WQ2, const float* __restrict__ bQ2,
    const float* __restrict__ WK1, const float* __restrict__ bK1,
    const float* __restrict__ WK2, const float* __restrict__ bK2,
    const float* __restrict__ WV,  const float* __restrict__ bV,
    float* __restrict__ q1n, float* __restrict__ q2n,
    float* __restrict__ k1n, float* __restrict__ k2n, float* __restrict__ vv)
{
  __shared__ float xv[TA][65], a1v[TA][65], a2v[TA][65];
  const int tid = threadIdx.x;
  const int t0 = blockIdx.x * TA;
  const int b  = t0 / 4800;
  const int nl0 = t0 % 4800;          // 16-aligned, block stays within one b
  {
    const float4* xg  = (const float4*)x;
    const float4* a1g = (const float4*)xa1;
    const float4* a2g = (const float4*)xa2;
    for (int i = tid; i < 256; i += 128) {
      int c = i >> 2, q = i & 3;
      int src = ((b*64 + c)*4800 + nl0)/4 + q;   // float4-aligned
      float4 xq = xg[src], a1q = a1g[src], a2q = a2g[src];
      int tt = q*4;
      xv[tt+0][c]=xq.x;  xv[tt+1][c]=xq.y;  xv[tt+2][c]=xq.z;  xv[tt+3][c]=xq.w;
      a1v[tt+0][c]=a1q.x; a1v[tt+1][c]=a1q.y; a1v[tt+2][c]=a1q.z; a1v[tt+3][c]=a1q.w;
      a2v[tt+0][c]=a2q.x; a2v[tt+1][c]=a2q.y; a2v[tt+2][c]=a2q.z; a2v[tt+3][c]=a2q.w;
    }
  }
  __syncthreads();
  const int d = tid;  // 0..127
  float aq1[TA], aq2[TA], ak1[TA], ak2[TA], av[TA];
  float b1 = bQ1[d], b2 = bQ2[d], b3 = bK1[d], b4 = bK2[d], b5 = bV[d];
  #pragma unroll
  for (int t = 0; t < TA; ++t) { aq1[t]=b1; aq2[t]=b2; ak1[t]=b3; ak2[t]=b4; av[t]=b5; }
  for (int c = 0; c < CHN; ++c) {
    float w1 = WQ1[c*DM + d], w2 = WQ2[c*DM + d], w3 = WK1[c*DM + d],
          w4 = WK2[c*DM + d], w5 = WV[c*DM + d];
    #pragma unroll
    for (int t = 0; t < TA; ++t) {
      float xc = xv[t][c], x1 = a1v[t][c], x2 = a2v[t][c];
      aq1[t] += x1*w1; aq2[t] += x2*w2; ak1[t] += xc*w3; ak2[t] += xc*w4; av[t] += xc*w5;
    }
  }
  const int h = d >> 4, dd = d & 15;
  #pragma unroll
  for (int t = 0; t < TA; ++t) {
    float s1 = aq1[t]*aq1[t], s2 = aq2[t]*aq2[t], s3 = ak1[t]*ak1[t], s4 = ak2[t]*ak2[t];
    #pragma unroll
    for (int m = 1; m < 16; m <<= 1) {
      s1 += __shfl_xor(s1, m); s2 += __shfl_xor(s2, m);
      s3 += __shfl_xor(s3, m); s4 += __shfl_xor(s4, m);
    }
    float i1 = 1.f/fmaxf(sqrtf(s1),1e-12f), i2 = 1.f/fmaxf(sqrtf(s2),1e-12f),
          i3 = 1.f/fmaxf(sqrtf(s3),1e-12f), i4 = 1.f/fmaxf(sqrtf(s4),1e-12f);
    int nl = nl0 + t;
    int n = nl / 12, l = nl % 12;
    int base = (((b*LW + l)*NH + h)*NPT + n)*HDM + dd;
    q1n[base] = aq1[t]*i1; q2n[base] = aq2[t]*i2;
    k1n[base] = ak1[t]*i3; k2n[base] = ak2[t]*i4; vv[base] = av[t];
  }
}

// ------------------------------------------------------------------
// Stage B: fused dual-cosine attention + exact top-k dual softmax + PV
// Grid: (b,h,l, split s of 100 rows) = 768 WGs x 256 threads
// k1/k2/v ALL in LDS (77 KB, 2 WGs/CU): LDS-resident operands are immune
// to the streaming-store L2 thrash (R3 regression: v-from-global doubled
// hbm_bytes). attn/p2 stores are NONTEMPORAL (never re-read; avoid
// RFO/allocation in L2).
// ------------------------------------------------------------------
__device__ __forceinline__ unsigned okey(float xf) {
  unsigned u = __float_as_uint(xf);
  return (u & 0x80000000u) ? ~u : (u | 0x80000000u);
}
__device__ __forceinline__ float dekey(unsigned k) {
  unsigned u = (k & 0x80000000u) ? (k & 0x7FFFFFFFu) : ~k;
  return __uint_as_float(u);
}

__global__ __launch_bounds__(256, 2) void stage_b(
    const float* __restrict__ q1n, const float* __restrict__ q2n,
    const float* __restrict__ k1n, const float* __restrict__ k2n,
    const float* __restrict__ vv,
    const float* __restrict__ temperature, const float* __restrict__ alphas,
    float* __restrict__ attn_o, float* __restrict__ p2_o, float* __restrict__ oa)
{
  // d-chunk planes, stride 401 float4 per plane: stride-1 b128 reads, conflict-free
  __shared__ float4 k1s[4*401], k2s[4*401], vs[4*401];
  int wg = blockIdx.x;
  const int s = wg & 3; wg >>= 2;
  const int l = wg % LW; wg /= LW;
  const int h = wg & 7; const int b = wg >> 3;
  const int tid = threadIdx.x, lane = tid & 63, wave = tid >> 6;

  const int slice = (b*LW + l)*NH + h;          // internal q/k/v layout [b][l][h]
  const int oslice = (b*NH + h)*LW + l;         // OUTPUT layout [b][h][l]
  const float4* k1g = (const float4*)(k1n + slice*NPT*HDM);
  const float4* k2g = (const float4*)(k2n + slice*NPT*HDM);
  const float4* vg  = (const float4*)(vv  + slice*NPT*HDM);
  for (int i = tid; i < NPT*4; i += 256) {
    int m = i >> 2, w4 = i & 3;
    k1s[w4*401 + m] = k1g[i];
    k2s[w4*401 + m] = k2g[i];
    vs [w4*401 + m] = vg[i];
  }
  __syncthreads();

  const float temp = temperature[h];
  float a0 = alphas[0], a1 = alphas[1];
  float amx = fmaxf(a0, a1);
  float e0 = __expf(a0 - amx), e1 = __expf(a1 - amx);
  float al0 = e0/(e0+e1), al1 = e1/(e0+e1);

  const float* q1base = q1n + slice*NPT*HDM;
  const float* q2base = q2n + slice*NPT*HDM;
  float* attn_base = attn_o + (size_t)oslice*NPT*NPT;
  float* p2_base   = p2_o   + (size_t)oslice*NPT*NPT;

  for (int bi = wave; bi < 25; bi += 4) {
    const int nb = s*100 + bi*4;    // rows nb..nb+3
    float sc[4][7];
    #pragma unroll
    for (int r = 0; r < 4; ++r)
      #pragma unroll
      for (int j = 0; j < 7; ++j) sc[r][j] = 0.f;

    // ---- scores: Q1.K1 + Q2.K2 over d (16+16), 4 rows x 7 m's/lane ----
    #pragma unroll
    for (int ch = 0; ch < 4; ++ch) {
      float4 q1c[4], q2c[4];
      #pragma unroll
      for (int r = 0; r < 4; ++r) {
        q1c[r] = *(const float4*)(q1base + (nb+r)*HDM + ch*4);
        q2c[r] = *(const float4*)(q2base + (nb+r)*HDM + ch*4);
      }
      #pragma unroll
      for (int j = 0; j < 7; ++j) {
        int m = lane + 64*j;
        if (j < 6 || lane < 16) {
          float4 kc1 = k1s[ch*401 + m];
          float4 kc2 = k2s[ch*401 + m];
          #pragma unroll
          for (int r = 0; r < 4; ++r) {
            sc[r][j] += q1c[r].x*kc1.x + q1c[r].y*kc1.y + q1c[r].z*kc1.z + q1c[r].w*kc1.w
                      + q2c[r].x*kc2.x + q2c[r].y*kc2.y + q2c[r].z*kc2.z + q2c[r].w*kc2.w;
          }
        }
      }
    }
    // ---- temperature + attn output (nontemporal streaming stores) ----
    #pragma unroll
    for (int r = 0; r < 4; ++r) {
      float* ap = attn_base + (nb + r)*NPT + lane;
      #pragma unroll
      for (int j = 0; j < 7; ++j) {
        sc[r][j] *= temp;
        if (j < 6 || lane < 16) __builtin_nontemporal_store(sc[r][j], ap + 64*j);
      }
    }
    // ---- per-row: exact top-k select (interleaved dual search) + softmax ----
    #pragma unroll
    for (int r = 0; r < 4; ++r) {
      unsigned key[7];
      unsigned kmx = 0u, kmn = 0xFFFFFFFFu;
      #pragma unroll
      for (int j = 0; j < 7; ++j) {
        bool valid = (j < 6) || (lane < 16);
        unsigned kk = valid ? okey(sc[r][j]) : 0u;
        key[j] = kk;
        kmx = kk > kmx ? kk : kmx;
        unsigned kn = valid ? kk : 0xFFFFFFFFu;
        kmn = kn < kmn ? kn : kmn;
      }
      #pragma unroll
      for (int m2 = 1; m2 < 64; m2 <<= 1) {
        unsigned ox = __shfl_xor(kmx, m2); kmx = ox > kmx ? ox : kmx;
        unsigned on = __shfl_xor(kmn, m2); kmn = on < kmn ? on : kmn;
      }
      float am = dekey(kmx);              // exact row max (for softmax)
      unsigned diff = kmx ^ kmn;
      unsigned p1, p2u;
      if (diff == 0u) {
        p1 = kmx; p2u = kmx;
      } else {
        int fd = 31 - __clz(diff);
        unsigned hi = (fd >= 31) ? 0u : (~0u << (fd+1));
        p1 = kmx & hi; p2u = p1;          // common prefix of all keys
        bool d1 = false, d2 = false;
        #pragma clang loop unroll(disable)
        for (int bit = fd; bit >= 0; --bit) {
          unsigned msk = 1u << bit;
          if (!d1) {
            unsigned T1 = p1 | msk;
            int c1 = 0;
            #pragma unroll
            for (int j = 0; j < 7; ++j) c1 += __popcll(__ballot(key[j] >= T1));
            if (c1 >= 200) { p1 = T1; d1 = (c1 == 200); }
          }
          if (!d2) {
            unsigned T2 = p2u | msk;
            int c2 = 0;
            #pragma unroll
            for (int j = 0; j < 7; ++j) c2 += __popcll(__ballot(key[j] >= T2));
            if (c2 >= 100) { p2u = T2; d2 = (c2 == 100); }
          }
          if (d1 & d2) break;
        }
      }
      float e[7]; float s1 = 0.f, s2 = 0.f;
      #pragma unroll
      for (int j = 0; j < 7; ++j) {
        e[j] = ((j < 6) || (lane < 16)) ? __expf(sc[r][j] - am) : 0.f;
        s1 += (key[j] >= p1)  ? e[j] : 0.f;
        s2 += (key[j] >= p2u) ? e[j] : 0.f;
      }
      #pragma unroll
      for (int m2 = 1; m2 < 64; m2 <<= 1) { s1 += __shfl_xor(s1, m2); s2 += __shfl_xor(s2, m2); }
      float rz1 = 1.f / s1, rz2 = 1.f / s2;
      float c1f = al0 * rz1, c2f = al1 * rz2;
      float* pp = p2_base + (nb + r)*NPT + lane;
      #pragma unroll
      for (int j = 0; j < 7; ++j) {
        float p2v = (key[j] >= p2u) ? e[j]*rz2 : 0.f;
        if ((j < 6) || (lane < 16)) __builtin_nontemporal_store(p2v, pp + 64*j);
        sc[r][j] = e[j] * (((key[j] >= p1) ? c1f : 0.f) + ((key[j] >= p2u) ? c2f : 0.f));
      }
    }
    // ---- PV: out[r][d] = sum_m w[r][m] * v[m][d]; v from LDS ----
    float buf[64];
    #pragma unroll
    for (int i = 0; i < 64; ++i) buf[i] = 0.f;
    #pragma unroll
    for (int j = 0; j < 7; ++j) {
      int m = lane + 64*j;
      if (j < 6 || lane < 16) {
        float4 w0 = vs[0*401+m], w1 = vs[1*401+m], w2 = vs[2*401+m], w3 = vs[3*401+m];
        #pragma unroll
        for (int r = 0; r < 4; ++r) {
          float wr = sc[r][j];
          buf[r*16+ 0] += wr*w0.x; buf[r*16+ 1] += wr*w0.y; buf[r*16+ 2] += wr*w0.z; buf[r*16+ 3] += wr*w0.w;
          buf[r*16+ 4] += wr*w1.x; buf[r*16+ 5] += wr*w1.y; buf[r*16+ 6] += wr*w1.z; buf[r*16+ 7] += wr*w1.w;
          buf[r*16+ 8] += wr*w2.x; buf[r*16+ 9] += wr*w2.y; buf[r*16+10] += wr*w2.z; buf[r*16+11] += wr*w2.w;
          buf[r*16+12] += wr*w3.x; buf[r*16+13] += wr*w3.y; buf[r*16+14] += wr*w3.z; buf[r*16+15] += wr*w3.w;
        }
      }
    }
    // ---- 64-element reduce-scatter across lanes (lane ends owning idx=lane) ----
    #pragma unroll
    for (int st = 0; st < 6; ++st) {
      int bsel = (lane >> st) & 1;
      #pragma unroll
      for (int u = 0; u < (64 >> (st+1)); ++u) {
        float lo = buf[2*u], hi = buf[2*u+1];
        float keep = bsel ? hi : lo;
        float send = bsel ? lo : hi;
        float recv = __shfl_xor(send, 1 << st);
        buf[u] = keep + recv;
      }
    }
    int rr = lane >> 4, ddd = lane & 15;
    oa[((size_t)b*4800 + (size_t)(nb + rr)*12 + l)*DM + h*HDM + ddd] = buf[0];
  }
}

// ------------------------------------------------------------------
// Stage C: Wo + residual + LN1 + FF + LN2 + coalesced transpose-out
// Grid: 300 WGs x 256 threads, 32 tokens/WG (token' = b*4800+n*12+l)
// ------------------------------------------------------------------
#define TC 32
__global__ __launch_bounds__(256, 2) void stage_c(
    const float* __restrict__ oa, const float* __restrict__ x,
    const float* __restrict__ Wo, const float* __restrict__ bo,
    const float* __restrict__ Wf1, const float* __restrict__ bf1,
    const float* __restrict__ Wf2, const float* __restrict__ bf2,
    const float* __restrict__ g1, const float* __restrict__ be1,
    const float* __restrict__ g2, const float* __restrict__ be2,
    float* __restrict__ outp)
{
  __shared__ float4 oa_lds[TC*32];   // 16 KB
  __shared__ float  xs[TC][65];      // 8.3 KB (x in, y out)
  __shared__ float4 y1_lds[TC*16];   // 8 KB
  __shared__ float4 act_lds[TC*64];  // 32 KB
  const int tid = threadIdx.x;
  const int t0 = blockIdx.x * TC;
  const int b = t0 / 4800, nl0 = t0 % 4800;   // 32 | 4800
  const float4* oag = (const float4*)(oa + t0*DM);
  for (int i = tid; i < TC*32; i += 256) oa_lds[i] = oag[i];
  {
    const float4* xg = (const float4*)x;
    for (int i = tid; i < 512; i += 256) {
      int c = i >> 3, q = i & 7;
      float4 xq = xg[((b*64 + c)*4800 + nl0)/4 + q];
      int tt = q*4;
      xs[tt+0][c]=xq.x; xs[tt+1][c]=xq.y; xs[tt+2][c]=xq.z; xs[tt+3][c]=xq.w;
    }
  }
  __syncthreads();

  const int c = tid & 63, g = tid >> 6;   // tokens tt = g + 4k, k=0..7
  float bo_c = bo[c], g1c = g1[c], be1c = be1[c], g2c = g2[c], be2c = be2[c], bf2c = bf2[c];

  // P1: o1 = oa @ Wo + bo
  float o1[8];
  #pragma unroll
  for (int k = 0; k < 8; ++k) o1[k] = bo_c;
  for (int d4 = 0; d4 < 32; ++d4) {
    float w0 = Wo[(4*d4+0)*CHN + c];
    float w1 = Wo[(4*d4+1)*CHN + c];
    float w2 = Wo[(4*d4+2)*CHN + c];
    float w3 = Wo[(4*d4+3)*CHN + c];
    #pragma unroll
    for (int k = 0; k < 8; ++k) {
      float4 u = oa_lds[(g + 4*k)*32 + d4];
      o1[k] += u.x*w0 + u.y*w1 + u.z*w2 + u.w*w3;
    }
  }
  // residual + LN1
  float y1r[8];
  #pragma unroll
  for (int k = 0; k < 8; ++k) {
    float val = o1[k] + xs[g + 4*k][c];
    float sm = val, sq = val*val;
    #pragma unroll
    for (int m2 = 1; m2 < 64; m2 <<= 1) { sm += __shfl_xor(sm, m2); sq += __shfl_xor(sq, m2); }
    float mean = sm * (1.f/64.f);
    float var = sq * (1.f/64.f) - mean*mean;
    float y = (val - mean) * rsqrtf(var + 1e-5f) * g1c + be1c;
    y1r[k] = y;
    ((float*)y1_lds)[(g + 4*k)*CHN + c] = y;
  }
  __syncthreads();

  float o2a[8];
  #pragma unroll
  for (int k = 0; k < 8; ++k) o2a[k] = 0.f;

  for (int fb = 0; fb < 4; ++fb) {
    // 2a: act = relu(y1 @ Wf1 + bf1) for 256 f's
    {
      const int ft = tid & 63, ga = tid >> 6;
      const int f = fb*256 + ft*4;
      float4 facc[8];
      float4 bb = *(const float4*)(bf1 + f);
      #pragma unroll
      for (int k = 0; k < 8; ++k) facc[k] = bb;
      for (int c4 = 0; c4 < 16; ++c4) {
        float4 w0 = *(const float4*)(Wf1 + (4*c4+0)*FFD + f);
        float4 w1 = *(const float4*)(Wf1 + (4*c4+1)*FFD + f);
        float4 w2 = *(const float4*)(Wf1 + (4*c4+2)*FFD + f);
        float4 w3 = *(const float4*)(Wf1 + (4*c4+3)*FFD + f);
        #pragma unroll
        for (int k = 0; k < 8; ++k) {
          float4 y4 = y1_lds[(ga + 4*k)*16 + c4];
          facc[k].x += y4.x*w0.x + y4.y*w1.x + y4.z*w2.x + y4.w*w3.x;
          facc[k].y += y4.x*w0.y + y4.y*w1.y + y4.z*w2.y + y4.w*w3.y;
          facc[k].z += y4.x*w0.z + y4.y*w1.z + y4.z*w2.z + y4.w*w3.z;
          facc[k].w += y4.x*w0.w + y4.y*w1.w + y4.z*w2.w + y4.w*w3.w;
        }
      }
      #pragma unroll
      for (int k = 0; k < 8; ++k) {
        float4 rv;
        rv.x = fmaxf(facc[k].x, 0.f); rv.y = fmaxf(facc[k].y, 0.f);
        rv.z = fmaxf(facc[k].z, 0.f); rv.w = fmaxf(facc[k].w, 0.f);
        act_lds[(ga + 4*k)*64 + ft] = rv;
      }
    }
    __syncthreads();
    // 2b: o2 += act @ Wf2
    for (int f4 = 0; f4 < 64; ++f4) {
      int f = fb*256 + f4*4;
      float w0 = Wf2[(f+0)*CHN + c];
      float w1 = Wf2[(f+1)*CHN + c];
      float w2 = Wf2[(f+2)*CHN + c];
      float w3 = Wf2[(f+3)*CHN + c];
      #pragma unroll
      for (int k = 0; k < 8; ++k) {
        float4 a4 = act_lds[(g + 4*k)*64 + f4];
        o2a[k] += a4.x*w0 + a4.y*w1 + a4.z*w2 + a4.w*w3;
      }
    }
    __syncthreads();
  }
  // P3: + bf2, residual y1, LN2 -> stash y into xs, then coalesced store
  #pragma unroll
  for (int k = 0; k < 8; ++k) {
    float val = y1r[k] + o2a[k] + bf2c;
    float sm = val, sq = val*val;
    #pragma unroll
    for (int m2 = 1; m2 < 64; m2 <<= 1) { sm += __shfl_xor(sm, m2); sq += __shfl_xor(sq, m2); }
    float mean = sm * (1.f/64.f);
    float var = sq * (1.f/64.f) - mean*mean;
    float y = (val - mean) * rsqrtf(var + 1e-5f) * g2c + be2c;
    xs[g + 4*k][c] = y;
  }
  __syncthreads();
  {
    float4* og = (float4*)outp;
    for (int i = tid; i < 512; i += 256) {
      int cc = i >> 3, q = i & 7;
      int tt = q*4;
      float4 yq;
      yq.x = xs[tt+0][cc]; yq.y = xs[tt+1][cc]; yq.z = xs[tt+2][cc]; yq.w = xs[tt+3][cc];
      og[((b*64 + cc)*4800 + nl0)/4 + q] = yq;
    }
  }
}

// ------------------------------------------------------------------
extern "C" void kernel_launch(void* const* d_in, const int* in_sizes, int n_in,
                              void* d_out, int out_size, void* d_ws, size_t ws_size,
                              hipStream_t stream) {
  const float* x    = (const float*)d_in[0];
  const float* xa1  = (const float*)d_in[1];
  const float* xa2  = (const float*)d_in[2];
  const float* WQ1  = (const float*)d_in[3];
  const float* bQ1  = (const float*)d_in[4];
  const float* WQ2  = (const float*)d_in[5];
  const float* bQ2  = (const float*)d_in[6];
  const float* WK1  = (const float*)d_in[7];
  const float* bK1  = (const float*)d_in[8];
  const float* WK2  = (const float*)d_in[9];
  const float* bK2  = (const float*)d_in[10];
  const float* WV   = (const float*)d_in[11];
  const float* bV   = (const float*)d_in[12];
  const float* Wo   = (const float*)d_in[13];
  const float* bo   = (const float*)d_in[14];
  const float* Wf1  = (const float*)d_in[15];
  const float* bf1  = (const float*)d_in[16];
  const float* Wf2  = (const float*)d_in[17];
  const float* bf2  = (const float*)d_in[18];
  const float* g1   = (const float*)d_in[19];
  const float* be1  = (const float*)d_in[20];
  const float* g2   = (const float*)d_in[21];
  const float* be2  = (const float*)d_in[22];
  const float* temp = (const float*)d_in[23];
  const float* alph = (const float*)d_in[24];

  float* outp   = (float*)d_out;
  float* attn_o = outp + (size_t)BSZ*CHN*NPT*LW;          // 614400
  float* p2_o   = attn_o + (size_t)BSZ*NH*LW*NPT*NPT;     // +30720000

  const size_t SLICE = (size_t)BSZ*LW*NH*NPT*HDM;         // 2457600
  float* w   = (float*)d_ws;
  float* q1n = w;             w += SLICE;
  float* q2n = w;             w += SLICE;
  float* k1n = w;             w += SLICE;
  float* k2n = w;             w += SLICE;
  float* vv  = w;             w += SLICE;
  float* oa  = w;             w += (size_t)NTOK*DM;

  stage_a<<<NTOK/TA, 128, 0, stream>>>(x, xa1, xa2, WQ1, bQ1, WQ2, bQ2,
                                       WK1, bK1, WK2, bK2, WV, bV,
                                       q1n, q2n, k1n, k2n, vv);
  stage_b<<<BSZ*NH*LW*4, 256, 0, stream>>>(q1n, q2n, k1n, k2n, vv,
                                           temp, alph, attn_o, p2_o, oa);
  stage_c<<<NTOK/TC, 256, 0, stream>>>(oa, x, Wo, bo, Wf1, bf1, Wf2, bf2,
                                       g1, be1, g2, be2, outp);
}